// Round 4
// baseline (106.455 us; speedup 1.0000x reference)
//
#include <hip/hip_runtime.h>
#include <cstdint>
#include <cstddef>

#define L_SEQ 2048
#define E_DIM 512
#define B_SZ 2
#define WIN 64
#define SCALE_QK 0.044194173824159216f  // 1/sqrt(512)

typedef __attribute__((ext_vector_type(8))) short short8;
typedef __attribute__((ext_vector_type(4))) float floatx4;

__device__ __forceinline__ unsigned short f2bf(float f) {
    unsigned int u = __float_as_uint(f);
    u += 0x7FFFu + ((u >> 16) & 1u);
    return (unsigned short)(u >> 16);
}

__device__ __forceinline__ void gload_lds16(const void* g, void* l) {
    __builtin_amdgcn_global_load_lds(
        (const __attribute__((address_space(1))) unsigned int*)g,
        (__attribute__((address_space(3))) unsigned int*)l,
        16, 0, 0);
}

// ---------------- fp32 -> bf16 conversion of x, Wq, Wk, Wv ----------------
__global__ __launch_bounds__(256) void cvt_kernel(
    const float* __restrict__ x, const float* __restrict__ wq,
    const float* __restrict__ wk, const float* __restrict__ wv,
    unsigned short* __restrict__ xb, unsigned short* __restrict__ wb)
{
    long i = (long)blockIdx.x * 256 + threadIdx.x;   // 0 .. 720895
    const float* src;
    unsigned short* dst;
    long off;
    if (i < 524288) {
        src = x; dst = xb; off = i;
    } else {
        long j = i - 524288;
        int w = (int)(j >> 16);
        off = j & 65535;
        src = (w == 0) ? wq : ((w == 1) ? wk : wv);
        dst = wb + (long)w * 262144;
    }
    float4 f = ((const float4*)src)[off];
    ushort4 o;
    o.x = f2bf(f.x); o.y = f2bf(f.y); o.z = f2bf(f.z); o.w = f2bf(f.w);
    ((ushort4*)dst)[off] = o;
}

// ---------------- QKV projection: m97-structure 128x128 tile, BK=64 --------
// C[m,n] = sum_k X[m,k] W[n,k] + bias[n].  global_load_lds width-16 staging
// into LINEAR LDS; XOR swizzle (colb ^= (row&7)<<4, an involution) applied to
// BOTH the global source address and the ds_read address (rule: both-sides-or-
// neither), killing the 8-way bank conflict of a linear [128][64] bf16 tile.
// 4 waves, each owns a 64x64 quadrant (4x4 16x16x32 frags).
// z==0 -> q[m][n], z==1 -> k[m][n], z==2 -> vT[n][m] (+bias over n).
// grid (32,4,3) = 384 blocks.
__global__ __launch_bounds__(256) void qkv_gemm(
    const unsigned short* __restrict__ xb,   // 4096 x 512
    const unsigned short* __restrict__ wb,   // 3 x (512 x 512), (N,K)
    const float* __restrict__ bq, const float* __restrict__ bk, const float* __restrict__ bv,
    unsigned short* __restrict__ q, unsigned short* __restrict__ k,
    unsigned short* __restrict__ vt)
{
    __shared__ __align__(16) char lds_raw[32768];
    unsigned short* As = (unsigned short*)lds_raw;          // [128][64] bf16, swizzled
    unsigned short* Bs = As + 8192;                         // [128][64] bf16, swizzled

    const int t = threadIdx.x;
    const int w = t >> 6, l = t & 63;
    const int m0 = blockIdx.x * 128, n0 = blockIdx.y * 128, z = blockIdx.z;
    const unsigned short* W = wb + (size_t)z * 262144;
    const float* bias = (z == 0) ? bq : ((z == 1) ? bk : bv);

    const int wr = w >> 1, wc = w & 1;        // wave quadrant (2x2 of 64x64)
    const int fr = l & 15, fq = l >> 4;

    // staging map: wave-instr p = w*4+j covers LDS bytes [p*1024, p*1024+1024);
    // lane's linear byte L = p*1024 + l*16; row = L>>7; colb = (L&127)^((row&7)<<4)
    int arow[4], acolb[4];
#pragma unroll
    for (int j = 0; j < 4; j++) {
        int L = (w * 4 + j) * 1024 + l * 16;
        int row = L >> 7;
        arow[j]  = row;
        acolb[j] = (L & 127) ^ ((row & 7) << 4);
    }
    const char* gA = (const char*)(xb + (size_t)m0 * 512);
    const char* gB = (const char*)(W  + (size_t)n0 * 512);

    float bv_[4];
#pragma unroll
    for (int j = 0; j < 4; j++) bv_[j] = bias[n0 + wc * 64 + j * 16 + fr];

    floatx4 acc[4][4] = {};

    for (int kt = 0; kt < 8; kt++) {
#pragma unroll
        for (int j = 0; j < 4; j++) {
            gload_lds16(gA + (size_t)arow[j] * 1024 + kt * 128 + acolb[j],
                        (char*)As + (w * 4 + j) * 1024 + l * 16);
            gload_lds16(gB + (size_t)arow[j] * 1024 + kt * 128 + acolb[j],
                        (char*)Bs + (w * 4 + j) * 1024 + l * 16);
        }
        __syncthreads();                       // compiler drains vmcnt before barrier

        short8 a[4][2], bfr[4][2];
#pragma unroll
        for (int i = 0; i < 4; i++)
#pragma unroll
            for (int kh = 0; kh < 2; kh++) {
                int row = wr * 64 + i * 16 + fr;
                int cb  = (kh * 64 + fq * 16) ^ ((row & 7) << 4);
                a[i][kh] = *(const short8*)((const char*)As + (row << 7) + cb);
            }
#pragma unroll
        for (int j = 0; j < 4; j++)
#pragma unroll
            for (int kh = 0; kh < 2; kh++) {
                int row = wc * 64 + j * 16 + fr;
                int cb  = (kh * 64 + fq * 16) ^ ((row & 7) << 4);
                bfr[j][kh] = *(const short8*)((const char*)Bs + (row << 7) + cb);
            }
#pragma unroll
        for (int kh = 0; kh < 2; kh++)
#pragma unroll
            for (int i = 0; i < 4; i++)
#pragma unroll
                for (int j = 0; j < 4; j++)
                    acc[i][j] = __builtin_amdgcn_mfma_f32_16x16x32_bf16(a[i][kh], bfr[j][kh], acc[i][j], 0, 0, 0);
        __syncthreads();
    }

    // ---- epilogue: 2 halves through a padded 64x136 LDS transpose buffer ----
#define TLD 136
    unsigned short* T = (unsigned short*)lds_raw;   // 64*136*2 = 17408 B <= 32768
    const int tr = t >> 2, tc = (t & 3) * 32;

    for (int h = 0; h < 2; h++) {
        if (h) __syncthreads();                // everyone done reading T of h=0
        if (z < 2) {
            if (wr == h) {
#pragma unroll
                for (int i = 0; i < 4; i++)
#pragma unroll
                    for (int j = 0; j < 4; j++)
#pragma unroll
                        for (int r = 0; r < 4; r++)
                            T[(i * 16 + fq * 4 + r) * TLD + wc * 64 + j * 16 + fr] =
                                f2bf(acc[i][j][r] + bv_[j]);
            }
        } else {
            if (wc == h) {                     // transpose: T[local n][local m]
#pragma unroll
                for (int i = 0; i < 4; i++)
#pragma unroll
                    for (int j = 0; j < 4; j++)
#pragma unroll
                        for (int r = 0; r < 4; r++)
                            T[(j * 16 + fr) * TLD + wr * 64 + i * 16 + fq * 4 + r] =
                                f2bf(acc[i][j][r] + bv_[j]);
            }
        }
        __syncthreads();

        uint4 u0 = *(const uint4*)&T[tr * TLD + tc];
        uint4 u1 = *(const uint4*)&T[tr * TLD + tc + 8];
        uint4 u2 = *(const uint4*)&T[tr * TLD + tc + 16];
        uint4 u3 = *(const uint4*)&T[tr * TLD + tc + 24];
        if (z < 2) {
            unsigned short* out = (z == 0) ? q : k;
            size_t o = (size_t)(m0 + h * 64 + tr) * 512 + n0 + tc;
            *(uint4*)&out[o]      = u0;
            *(uint4*)&out[o + 8]  = u1;
            *(uint4*)&out[o + 16] = u2;
            *(uint4*)&out[o + 24] = u3;
        } else {
            size_t o = (size_t)(n0 + h * 64 + tr) * 4096 + m0 + tc;
            *(uint4*)&vt[o]      = u0;
            *(uint4*)&vt[o + 8]  = u1;
            *(uint4*)&vt[o + 16] = u2;
            *(uint4*)&vt[o + 24] = u3;
        }
    }
}

// ---------------- fused attention: 8 waves per 16-row Q-tile ----------------
// grid (128 Qtiles, 2 b), 512 threads. Wave w computes score n-tile w (wave 0
// also tile 8) into a shared fp32 LDS S-tile; one barrier; every wave
// redundantly computes the row-softmax from LDS; wave w runs PV for E-cols
// [64w, 64w+64).  All global loads unconditional (clamped addresses) and
// batched; masking done on values (-1e30 -> P=0).
#define SLD 164   // LDS row stride (fp32): 164%32=4 -> 2-way conflicts max on row reads
__global__ __launch_bounds__(512) void attn_fused(
    const unsigned short* __restrict__ qb, const unsigned short* __restrict__ kb,
    const unsigned short* __restrict__ vt, float* __restrict__ out)
{
    __shared__ __align__(16) float Sl[16 * SLD];   // 10.5 KB

    const int t = threadIdx.x;
    const int w = t >> 6, l = t & 63;
    const int fr = l & 15, fq = l >> 4;
    const int Q0 = blockIdx.x * 16;
    const int b  = blockIdx.y;
    const int R0 = Q0 - WIN;

    // ---- scores: wave w handles n-tile(s) {w, w+8} (only wave 0 gets a second)
    {
        const unsigned short* qrow = qb + (size_t)(b * L_SEQ + Q0 + fr) * 512 + fq * 8;
        short8 qf[16];
#pragma unroll
        for (int ks = 0; ks < 16; ks++) qf[ks] = *(const short8*)(qrow + ks * 32);

        for (int nt = w; nt < 9; nt += 8) {
            const int tok = R0 + nt * 16 + fr;
            const bool kvalid = (tok >= 0) && (tok < L_SEQ);
            const int tokc = min(max(tok, 0), L_SEQ - 1);        // clamped: always a real row
            const unsigned short* krow = kb + (size_t)(b * L_SEQ + tokc) * 512 + fq * 8;

            floatx4 acc0 = {}, acc1 = {};                        // 2 chains (8-deep, not 16)
            short8 bfr[8];
#pragma unroll
            for (int ks = 0; ks < 8; ks++) bfr[ks] = *(const short8*)(krow + ks * 32);
#pragma unroll
            for (int ks = 0; ks < 8; ks++)
                acc0 = __builtin_amdgcn_mfma_f32_16x16x32_bf16(qf[ks], bfr[ks], acc0, 0, 0, 0);
#pragma unroll
            for (int ks = 0; ks < 8; ks++) bfr[ks] = *(const short8*)(krow + (8 + ks) * 32);
#pragma unroll
            for (int ks = 0; ks < 8; ks++)
                acc1 = __builtin_amdgcn_mfma_f32_16x16x32_bf16(qf[8 + ks], bfr[ks], acc1, 0, 0, 0);

            const int jg = nt * 16 + fr;
#pragma unroll
            for (int r = 0; r < 4; r++) {
                int qq = fq * 4 + r;    // C/D layout: col=lane&15, row=(lane>>4)*4+r
                bool valid = kvalid && (jg >= qq) && (jg <= qq + 128);
                Sl[qq * SLD + jg] = valid ? (acc0[r] + acc1[r]) * SCALE_QK : -1e30f;
            }
        }
    }
    __syncthreads();

    // ---- softmax (per-wave redundant): lane covers row fr, cols fq*8 + ks*32 + j
    const float* Srow = &Sl[fr * SLD + fq * 8];
    float sv[5][8];
#pragma unroll
    for (int ks = 0; ks < 5; ks++) {
        float4 u0 = *(const float4*)(Srow + ks * 32);
        float4 u1 = *(const float4*)(Srow + ks * 32 + 4);
        sv[ks][0] = u0.x; sv[ks][1] = u0.y; sv[ks][2] = u0.z; sv[ks][3] = u0.w;
        sv[ks][4] = u1.x; sv[ks][5] = u1.y; sv[ks][6] = u1.z; sv[ks][7] = u1.w;
    }
    if (fq >= 2) {                    // cols 144..159: unwritten pad
#pragma unroll
        for (int j = 0; j < 8; j++) sv[4][j] = -1e30f;
    }
    float m = -1e30f;
#pragma unroll
    for (int ks = 0; ks < 5; ks++)
#pragma unroll
        for (int j = 0; j < 8; j++) m = fmaxf(m, sv[ks][j]);
    m = fmaxf(m, __shfl_xor(m, 16));
    m = fmaxf(m, __shfl_xor(m, 32));
    float sum = 0.f;
#pragma unroll
    for (int ks = 0; ks < 5; ks++)
#pragma unroll
        for (int j = 0; j < 8; j++) { float e = __expf(sv[ks][j] - m); sv[ks][j] = e; sum += e; }
    sum += __shfl_xor(sum, 16);
    sum += __shfl_xor(sum, 32);
    float inv = 1.f / sum;

    short8 a[5];     // P in A-frag layout: row fr, k-pos fq*8+j within 32-slice ks
#pragma unroll
    for (int ks = 0; ks < 5; ks++)
#pragma unroll
        for (int j = 0; j < 8; j++) a[ks][j] = (short)f2bf(sv[ks][j] * inv);

    // ---- PV: wave w owns E-cols [64w, 64w+64); loads clamped + batched (P=0 masks OOB)
    const int EC = w * 64;
    int tkc[5];
#pragma unroll
    for (int ks = 0; ks < 5; ks++) {
        int tok0 = R0 + ks * 32 + fq * 8;              // mod-8 aligned granule
        tkc[ks] = min(max(tok0, 0), L_SEQ - 8);        // clamp keeps 16B alignment
    }
    floatx4 oa[4] = {};
#pragma unroll
    for (int et = 0; et < 4; et++) {
        const unsigned short* vrow = vt + (size_t)(EC + et * 16 + fr) * 4096 + b * L_SEQ;
        short8 vfr[5];
#pragma unroll
        for (int ks = 0; ks < 5; ks++) vfr[ks] = *(const short8*)(vrow + tkc[ks]);
#pragma unroll
        for (int ks = 0; ks < 5; ks++)
            oa[et] = __builtin_amdgcn_mfma_f32_16x16x32_bf16(a[ks], vfr[ks], oa[et], 0, 0, 0);
    }

    float* op = out + (size_t)b * L_SEQ * E_DIM;
#pragma unroll
    for (int et = 0; et < 4; et++)
#pragma unroll
        for (int r = 0; r < 4; r++)
            op[(size_t)(Q0 + fq * 4 + r) * 512 + EC + et * 16 + fr] = oa[et][r];
}

// ---------------- launch ----------------
extern "C" void kernel_launch(void* const* d_in, const int* in_sizes, int n_in,
                              void* d_out, int out_size, void* d_ws, size_t ws_size,
                              hipStream_t stream)
{
    const float* x  = (const float*)d_in[0];
    const float* Wq = (const float*)d_in[1];
    const float* bq = (const float*)d_in[2];
    const float* Wk = (const float*)d_in[3];
    const float* bk = (const float*)d_in[4];
    const float* Wv = (const float*)d_in[5];
    const float* bv = (const float*)d_in[6];
    float* out = (float*)d_out;

    char* ws = (char*)d_ws;
    unsigned short* qb = (unsigned short*)(ws);                  // 4 MB bf16 q
    unsigned short* kb = (unsigned short*)(ws + 4194304);        // 4 MB bf16 k
    unsigned short* vt = (unsigned short*)(ws + 8388608);        // 4 MB bf16 v^T [e][tok]
    unsigned short* xb = (unsigned short*)(ws + 12582912);       // 4 MB bf16 x
    unsigned short* wb = (unsigned short*)(ws + 16777216);       // 1.5 MB bf16 W

    cvt_kernel<<<2816, 256, 0, stream>>>(x, Wq, Wk, Wv, xb, wb);
    qkv_gemm<<<dim3(32, 4, 3), 256, 0, stream>>>(xb, wb, bq, bk, bv, qb, kb, vt);
    attn_fused<<<dim3(128, 2), 512, 0, stream>>>(qb, kb, vt, out);
}